// Round 12
// baseline (370.768 us; speedup 1.0000x reference)
//
#include <hip/hip_runtime.h>
#include <hip/hip_bf16.h>

// Problem constants (B,T,S,D = 32,1024,1024,512)
#define B_ 32
#define T_ 1024
#define S_ 1024
#define D_ 512
#define M_ (B_*T_)       // 32768 GEMM rows
#define N_ D_            // 512  GEMM cols
#define K_ (2*D_)        // 1024 GEMM reduction

typedef __attribute__((ext_vector_type(8))) short bf16x8;  // 8 bf16 = 4 VGPRs
typedef __attribute__((ext_vector_type(4))) float f32x4;

__device__ inline unsigned short f2bf(float x) {
    union { float f; unsigned u; } v; v.f = x;
    unsigned r = v.u + 0x7FFFu + ((v.u >> 16) & 1u);   // RNE
    return (unsigned short)(r >> 16);
}

// pack 2 f32 -> 2 bf16 (RNE), packed in 32 bits
__device__ inline unsigned cvt2bf(float lo, float hi) {
#if __has_builtin(__builtin_amdgcn_cvt_pk_bf16_f32)
    typedef __attribute__((ext_vector_type(2))) __bf16 bf2;
    union { bf2 v; unsigned u; } r;
    r.v = __builtin_amdgcn_cvt_pk_bf16_f32(lo, hi);
    return r.u;
#else
    return (unsigned)f2bf(lo) | ((unsigned)f2bf(hi) << 16);
#endif
}

// fast tanh: 1 - 2/(e^{2x}+1) via hw exp2 + rcp. rel err ~1e-7, exact sat at +-1.
__device__ inline float fast_tanh(float x) {
#if __has_builtin(__builtin_amdgcn_exp2f) && __has_builtin(__builtin_amdgcn_rcpf)
    const float e = __builtin_amdgcn_exp2f(x * 2.885390082f);   // e^{2x}
    const float r = __builtin_amdgcn_rcpf(e + 1.0f);
    return 1.0f - 2.0f * r;
#else
    return tanhf(x);
#endif
}

// ---------------------------------------------------------------------------
// Kernel 1: alignment scan -> jbuf.
// ---------------------------------------------------------------------------
__global__ void align_kernel(const int* __restrict__ iv, int* __restrict__ jbuf) {
    const int b = blockIdx.x;          // 32 blocks x 64 threads
    const int lane = threadIdx.x;      // 16 tokens per lane
    const int* row = iv + b * T_;
    int f[16];
    int local = 0;
    const int t0 = lane * 16;
    #pragma unroll
    for (int q = 0; q < 16; ++q) {
        const int t = t0 + q;
        const int tok = row[t];
        const int fl = (t > 0 && (tok == 1 || tok == 2)) ? 1 : 0;
        f[q] = fl;
        local += fl;
    }
    int incl = local;
    #pragma unroll
    for (int off = 1; off < 64; off <<= 1) {
        const int up = __shfl_up(incl, off, 64);
        if (lane >= off) incl += up;
    }
    int run = incl - local;            // exclusive prefix at this lane's first token
    #pragma unroll
    for (int q = 0; q < 16; ++q) {
        const int t = t0 + q;
        run += f[q];
        int j;
        if (t == 0) {
            j = 0;                     // attn[b,0,0] = 1 always
        } else {
            j = t - run - 1;
            if (j < 0) j += S_;        // torch negative-index wrap
        }
        jbuf[b * T_ + t] = j;
    }
}

// ---------------------------------------------------------------------------
// Kernel 2: W [512,1024] f32 -> bf16
// ---------------------------------------------------------------------------
__global__ void pack_w(const float* __restrict__ W, unsigned short* __restrict__ Wbf) {
    const int idx = blockIdx.x * blockDim.x + threadIdx.x;   // N_*K_/8 threads
    const f32x4 a = ((const f32x4*)W)[idx * 2];
    const f32x4 c = ((const f32x4*)W)[idx * 2 + 1];
    union { bf16x8 v; unsigned u[4]; } pk;
    pk.u[0] = cvt2bf(a[0], a[1]); pk.u[1] = cvt2bf(a[2], a[3]);
    pk.u[2] = cvt2bf(c[0], c[1]); pk.u[3] = cvt2bf(c[2], c[3]);
    *(bf16x8*)(Wbf + (size_t)idx * 8) = pk.v;
}

// ---------------------------------------------------------------------------
// Kernel 3: GEMM 256x256, grid = 256 blocks (1/CU, ONE generation).
//
// R17 = R16 + full T3/T4 counted-vmcnt pipeline. The two failure modes that
// killed this pipeline in R6-R10 are structurally gone at this grid:
//  - spill: (512,2) = 1 block/CU -> 256 VGPR/wave budget (was 124 + ~40 dbuf)
//  - generational convoy drift: grid = 256 = one generation, all blocks
//    resident from t=0; NT writes bypass L2; inputs (192 MB) fit L3.
//
// Per K-sub-iter (As/Bs double-buffered, ONE barrier, static fa0/fa1):
//   DMA_B(i+1) -> Bs[p^1]       [4 loads, oldest]
//   LOAD_A(i+2) -> fa[p]        [8 loads, in flight ACROSS the barrier]
//   STAGE_A(i+1): cvt fa[p^1] -> As[p^1]   (compiler waits A(i+1) only)
//   MFMA on As[p], Bs[p]        (B drain + A flight hide under it)
//   s_waitcnt vmcnt(8) lgkm(0)  (drains exactly B(i+1); A(i+2) stays out)
//   s_barrier
// Count check (steady state at the wait): [B(i+1)x4, A(i+2)x8] = 12 ->
// vmcnt(8) retires the 4 oldest = B exactly. Hazards: every LDS buffer
// write-after-read pair is separated by the barrier (As[p^1] last read by
// MFMA(i-1), Bs[p^1] same).
// ---------------------------------------------------------------------------
#define BM 256
#define BN 256
#define BK 64
#define NIT (K_ / BK)                    // 16
#define KMAX (K_ - BK)                   // 960
#define NGEMM ((M_ / BM) * (N_ / BN))    // 128*2 = 256

__global__ __launch_bounds__(512, 2)
void gemm_attn(const unsigned short* __restrict__ Wbf,
               const float* __restrict__ bias,
               float* __restrict__ out,
               float* __restrict__ attn,
               const float* __restrict__ ctx,
               const float* __restrict__ outp,
               const int* __restrict__ jbuf) {
    const int bx = blockIdx.x;
    const int tid = threadIdx.x;

    __shared__ unsigned short As[2][BM * BK];   // 2 x 32 KB
    __shared__ unsigned short Bs[2][BN * BK];   // 2 x 32 KB  (128 KB total)

    // ---------------- GEMM tile 256x256 ----------------
    const int lane = tid & 63;
    const int wave = tid >> 6;                   // 0..7
    const int wm = wave >> 1, wn = wave & 1;     // 4x2 waves -> 64x128 each
    const int l16 = lane & 15, quad = lane >> 4;

    // sibling-adjacent same-XCD map: bn-pair of each bm spaced 8 apart.
    const int xcd = bx & 7;
    const int bn  = (bx >> 3) & 1;               // 2 n-tiles of 256
    const int bm  = ((bx >> 4) << 3) | xcd;      // 128 m-tiles of 256
    const int mBase = bm * BM;
    const int nBase = bn * BN;

    // A staging: chunk c = it*512+tid, row = it*64 + (tid>>3), g = tid&7.
    const int g    = tid & 7;
    const int rsub = tid >> 3;                   // 0..63
    const int sw   = g ^ (rsub & 7);             // swizzle, it-invariant (64%8==0)
    const float* actx[4];
    const float* aout[4];
    const unsigned short* bSrc[4];
    #pragma unroll
    for (int it = 0; it < 4; ++it) {
        const int r = it * 64 + rsub;
        const int m = mBase + r;
        const int jm = jbuf[m];
        actx[it] = ctx + ((size_t)((m >> 10) * S_ + jm)) * D_ + g * 8;
        aout[it] = outp + (size_t)m * D_ - D_ + g * 8;      // add ko>=512
        // B: row&7 == rsub&7 -> source granule == sw (pre-swizzled, linear dest)
        bSrc[it] = Wbf + (size_t)(nBase + r) * K_ + sw * 8;
    }

    f32x4 acc[4][8] = {};
    f32x4 fa0[4][2], fa1[4][2];

#define LOAD_A(FA, KO) do {                                                    \
    const int _koa = (KO);                                                     \
    _Pragma("unroll")                                                          \
    for (int _it = 0; _it < 4; ++_it) {                                        \
        const float* _src = (_koa < D_) ? (actx[_it] + _koa) : (aout[_it] + _koa); \
        FA[_it][0] = ((const f32x4*)_src)[0];                                  \
        FA[_it][1] = ((const f32x4*)_src)[1];                                  \
    }                                                                          \
} while (0)

#define DMA_B(P, KO) do {                                                      \
    const int _kob = (KO);                                                     \
    _Pragma("unroll")                                                          \
    for (int _it = 0; _it < 4; ++_it) {                                        \
        __builtin_amdgcn_global_load_lds(                                      \
            (const __attribute__((address_space(1))) void*)(bSrc[_it] + _kob), \
            (__attribute__((address_space(3))) void*)(&Bs[P][(_it * 512 + tid) * 8]), \
            16, 0, 0);                                                         \
    }                                                                          \
} while (0)

#define STAGE_A(P, FA) do {                                                    \
    _Pragma("unroll")                                                          \
    for (int _it = 0; _it < 4; ++_it) {                                        \
        union { bf16x8 v; unsigned u[4]; } _pk;                                \
        _pk.u[0] = cvt2bf(FA[_it][0][0], FA[_it][0][1]);                       \
        _pk.u[1] = cvt2bf(FA[_it][0][2], FA[_it][0][3]);                       \
        _pk.u[2] = cvt2bf(FA[_it][1][0], FA[_it][1][1]);                       \
        _pk.u[3] = cvt2bf(FA[_it][1][2], FA[_it][1][3]);                       \
        *(bf16x8*)&As[P][(_it * 512 + rsub * 8 + sw) * 8] = _pk.v;             \
    }                                                                          \
} while (0)

#define MFMA_PH(P) do {                                                        \
    _Pragma("unroll")                                                          \
    for (int _ks = 0; _ks < 2; ++_ks) {                                        \
        bf16x8 _af[4], _bfr[8];                                                \
        const int _q = _ks * 4 + quad;                                         \
        _Pragma("unroll")                                                      \
        for (int _mt = 0; _mt < 4; ++_mt) {                                    \
            const int _r = wm * 64 + _mt * 16 + l16;                           \
            _af[_mt] = *(const bf16x8*)&As[P][(_r * 8 + (_q ^ (_r & 7))) * 8]; \
        }                                                                      \
        _Pragma("unroll")                                                      \
        for (int _nt = 0; _nt < 8; ++_nt) {                                    \
            const int _rb = wn * 128 + _nt * 16 + l16;                         \
            _bfr[_nt] = *(const bf16x8*)&Bs[P][(_rb * 8 + (_q ^ (_rb & 7))) * 8]; \
        }                                                                      \
        _Pragma("unroll")                                                      \
        for (int _mt = 0; _mt < 4; ++_mt)                                      \
            _Pragma("unroll")                                                  \
            for (int _nt = 0; _nt < 8; ++_nt)                                  \
                acc[_mt][_nt] = __builtin_amdgcn_mfma_f32_16x16x32_bf16(       \
                    _af[_mt], _bfr[_nt], acc[_mt][_nt], 0, 0, 0);              \
    }                                                                          \
} while (0)

    // -------- prologue: tile 0 staged, A(1) in flight across the barrier ---
    LOAD_A(fa0, 0);                            // A(0)  [8]
    DMA_B(0, 0);                               // B(0)  [4]
    __builtin_amdgcn_sched_barrier(0);
    LOAD_A(fa1, BK);                           // A(1)  [8] stays in flight
    __builtin_amdgcn_sched_barrier(0);
    STAGE_A(0, fa0);                           // waits A(0) only (vmcnt<=12)
    asm volatile("s_waitcnt vmcnt(8) lgkmcnt(0)" ::: "memory");  // drain B(0)
    __builtin_amdgcn_sched_barrier(0);
    __builtin_amdgcn_s_barrier();
    __builtin_amdgcn_sched_barrier(0);

    #pragma unroll 1
    for (int i = 0; i < NIT; i += 2) {
        const int ko = i * BK;
        const int k2 = (ko + 2 * BK > KMAX) ? KMAX : ko + 2 * BK;
        const int k3 = (ko + 3 * BK > KMAX) ? KMAX : ko + 3 * BK;

        // ---- even sub-iter: compute tile i (buf0); stage i+1 (buf1) ----
        DMA_B(1, ko + BK);                     // B(i+1) [4, oldest]
        __builtin_amdgcn_sched_barrier(0);
        LOAD_A(fa0, k2);                       // A(i+2) [8, across barrier]
        __builtin_amdgcn_sched_barrier(0);
        STAGE_A(1, fa1);                       // cvt A(i+1) (waits its loads)
        MFMA_PH(0);
        asm volatile("s_waitcnt vmcnt(8) lgkmcnt(0)" ::: "memory"); // drain B(i+1)
        __builtin_amdgcn_sched_barrier(0);
        __builtin_amdgcn_s_barrier();
        __builtin_amdgcn_sched_barrier(0);

        // ---- odd sub-iter: compute tile i+1 (buf1); stage i+2 (buf0) ----
        DMA_B(0, k2);                          // B(i+2) (tail: dup, unread)
        __builtin_amdgcn_sched_barrier(0);
        LOAD_A(fa1, k3);                       // A(i+3) (tail: dup, unread)
        __builtin_amdgcn_sched_barrier(0);
        STAGE_A(0, fa0);                       // cvt A(i+2)
        MFMA_PH(1);
        asm volatile("s_waitcnt vmcnt(8) lgkmcnt(0)" ::: "memory");
        __builtin_amdgcn_sched_barrier(0);
        __builtin_amdgcn_s_barrier();
        __builtin_amdgcn_sched_barrier(0);
    }

#undef LOAD_A
#undef DMA_B
#undef STAGE_A
#undef MFMA_PH

    // ---- epilogue part 1: attn one-hot, 128 rows per block (bn picks half
    // of the 256-row m-panel). NT fire-and-forget; flies under the tanh VALU.
    {
        const int aBase = mBase + bn * 128;
        const int col  = tid & 255;            // f32x4 column (256 per row)
        const int half = tid >> 8;             // 0..1: row parity
        #pragma unroll 4
        for (int r = 0; r < 64; ++r) {
            const int row = aBase + r * 2 + half;
            const int j = jbuf[row];           // wave-uniform broadcast
            f32x4 v = {0.f, 0.f, 0.f, 0.f};
            if ((j >> 2) == col) v[j & 3] = 1.0f;
            __builtin_nontemporal_store(v, ((f32x4*)(attn + (size_t)row * S_)) + col);
        }
    }

    // ---- epilogue part 2: fast_tanh(acc + bias), fp32 NT store
    #pragma unroll
    for (int nt = 0; nt < 8; ++nt) {
        const int n = nBase + wn * 128 + nt * 16 + l16;
        const float bv = bias[n];
        #pragma unroll
        for (int mt = 0; mt < 4; ++mt) {
            #pragma unroll
            for (int r = 0; r < 4; ++r) {
                const int m = mBase + wm * 64 + mt * 16 + quad * 4 + r;
                const float val = fast_tanh(acc[mt][nt][r] + bv);
                __builtin_nontemporal_store(val, &out[(size_t)m * N_ + n]);
            }
        }
    }
}

// ---------------------------------------------------------------------------
extern "C" void kernel_launch(void* const* d_in, const int* in_sizes, int n_in,
                              void* d_out, int out_size, void* d_ws, size_t ws_size,
                              hipStream_t stream) {
    const int*   iv   = (const int*)d_in[0];    // input_var [B,T]
    const float* outp = (const float*)d_in[1];  // output   [B,T,D]
    const float* ctx  = (const float*)d_in[2];  // context  [B,S,D]
    // d_in[3] = di (unused by reference body)
    const float* W    = (const float*)d_in[4];  // [D, 2D]
    const float* bias = (const float*)d_in[5];  // [D]

    float* out  = (float*)d_out;                       // [B,T,D]
    float* attn = out + (size_t)M_ * N_;               // [B,T,S]

    // workspace layout: j[M_] int32 | Wbf[N_*K_] bf16   (~1.1 MB total)
    int* jbuf = (int*)d_ws;
    unsigned short* Wbf = (unsigned short*)((char*)d_ws + (size_t)M_ * 4);

    align_kernel<<<B_, 64, 0, stream>>>(iv, jbuf);
    pack_w<<<(N_ * K_ / 8) / 256, 256, 0, stream>>>(W, Wbf);
    gemm_attn<<<NGEMM, 512, 0, stream>>>(Wbf, bias, out, attn, ctx, outp, jbuf);
}

// Round 13
// 322.902 us; speedup vs baseline: 1.1482x; 1.1482x over previous
//
#include <hip/hip_runtime.h>
#include <hip/hip_bf16.h>

// Problem constants (B,T,S,D = 32,1024,1024,512)
#define B_ 32
#define T_ 1024
#define S_ 1024
#define D_ 512
#define M_ (B_*T_)       // 32768 GEMM rows
#define N_ D_            // 512  GEMM cols
#define K_ (2*D_)        // 1024 GEMM reduction

typedef __attribute__((ext_vector_type(8))) short bf16x8;  // 8 bf16 = 4 VGPRs
typedef __attribute__((ext_vector_type(4))) float f32x4;

__device__ inline unsigned short f2bf(float x) {
    union { float f; unsigned u; } v; v.f = x;
    unsigned r = v.u + 0x7FFFu + ((v.u >> 16) & 1u);   // RNE
    return (unsigned short)(r >> 16);
}

// pack 2 f32 -> 2 bf16 (RNE), packed in 32 bits
__device__ inline unsigned cvt2bf(float lo, float hi) {
#if __has_builtin(__builtin_amdgcn_cvt_pk_bf16_f32)
    typedef __attribute__((ext_vector_type(2))) __bf16 bf2;
    union { bf2 v; unsigned u; } r;
    r.v = __builtin_amdgcn_cvt_pk_bf16_f32(lo, hi);
    return r.u;
#else
    return (unsigned)f2bf(lo) | ((unsigned)f2bf(hi) << 16);
#endif
}

// fast tanh: 1 - 2/(e^{2x}+1) via hw exp2 + rcp. rel err ~1e-7, exact sat at +-1.
__device__ inline float fast_tanh(float x) {
#if __has_builtin(__builtin_amdgcn_exp2f) && __has_builtin(__builtin_amdgcn_rcpf)
    const float e = __builtin_amdgcn_exp2f(x * 2.885390082f);   // e^{2x}
    const float r = __builtin_amdgcn_rcpf(e + 1.0f);
    return 1.0f - 2.0f * r;
#else
    return tanhf(x);
#endif
}

// ---------------------------------------------------------------------------
// Kernel 1: alignment scan -> jbuf.
// ---------------------------------------------------------------------------
__global__ void align_kernel(const int* __restrict__ iv, int* __restrict__ jbuf) {
    const int b = blockIdx.x;          // 32 blocks x 64 threads
    const int lane = threadIdx.x;      // 16 tokens per lane
    const int* row = iv + b * T_;
    int f[16];
    int local = 0;
    const int t0 = lane * 16;
    #pragma unroll
    for (int q = 0; q < 16; ++q) {
        const int t = t0 + q;
        const int tok = row[t];
        const int fl = (t > 0 && (tok == 1 || tok == 2)) ? 1 : 0;
        f[q] = fl;
        local += fl;
    }
    int incl = local;
    #pragma unroll
    for (int off = 1; off < 64; off <<= 1) {
        const int up = __shfl_up(incl, off, 64);
        if (lane >= off) incl += up;
    }
    int run = incl - local;            // exclusive prefix at this lane's first token
    #pragma unroll
    for (int q = 0; q < 16; ++q) {
        const int t = t0 + q;
        run += f[q];
        int j;
        if (t == 0) {
            j = 0;                     // attn[b,0,0] = 1 always
        } else {
            j = t - run - 1;
            if (j < 0) j += S_;        // torch negative-index wrap
        }
        jbuf[b * T_ + t] = j;
    }
}

// ---------------------------------------------------------------------------
// Kernel 2: W [512,1024] f32 -> bf16
// ---------------------------------------------------------------------------
__global__ void pack_w(const float* __restrict__ W, unsigned short* __restrict__ Wbf) {
    const int idx = blockIdx.x * blockDim.x + threadIdx.x;   // N_*K_/8 threads
    const f32x4 a = ((const f32x4*)W)[idx * 2];
    const f32x4 c = ((const f32x4*)W)[idx * 2 + 1];
    union { bf16x8 v; unsigned u[4]; } pk;
    pk.u[0] = cvt2bf(a[0], a[1]); pk.u[1] = cvt2bf(a[2], a[3]);
    pk.u[2] = cvt2bf(c[0], c[1]); pk.u[3] = cvt2bf(c[2], c[3]);
    *(bf16x8*)(Wbf + (size_t)idx * 8) = pk.v;
}

// ---------------------------------------------------------------------------
// Kernel 3: GEMM 256x256, grid = 256 blocks (1/CU, ONE generation).
//
// R18 = R16 (champion structure, reverted from R17's spilling pipeline) with
// the attn one-hot writes DISTRIBUTED INTO THE K-LOOP: 8 rows per iteration
// (16 x 8 = the block's 128-row quota), issued right after barrier 1 next to
// the A-prefetch, retired by barrier 2's natural vmcnt(0) drain with the
// ~620cy MFMA phase as cover. At 1 block/CU the epilogue writes were fully
// SERIAL (~25-30us of the 121us kernel); interleaving them with the loop's
// existing stall windows reclaims most of that without touching registers,
// LDS, or the proven full-drain pacing.
//
// K-loop per iter:
//   DMA_B(i) -> STAGE_A(i)(cvt, fa prefetched) -> sync (drain B+ds_writes)
//   -> ATTN rows 8i..8i+8 (NT) + LOAD_A(i+1) (both fly under MFMA)
//   -> MFMA 64/wave -> sync (drain A + attn stores)
// ---------------------------------------------------------------------------
#define BM 256
#define BN 256
#define BK 64
#define NIT (K_ / BK)                    // 16
#define KMAX (K_ - BK)                   // 960
#define NGEMM ((M_ / BM) * (N_ / BN))    // 128*2 = 256

__global__ __launch_bounds__(512, 2)
void gemm_attn(const unsigned short* __restrict__ Wbf,
               const float* __restrict__ bias,
               float* __restrict__ out,
               float* __restrict__ attn,
               const float* __restrict__ ctx,
               const float* __restrict__ outp,
               const int* __restrict__ jbuf) {
    const int bx = blockIdx.x;
    const int tid = threadIdx.x;

    __shared__ unsigned short As[BM * BK];   // 32 KB
    __shared__ unsigned short Bs[BN * BK];   // 32 KB

    // ---------------- GEMM tile 256x256 ----------------
    const int lane = tid & 63;
    const int wave = tid >> 6;                   // 0..7
    const int wm = wave >> 1, wn = wave & 1;     // 4x2 waves -> 64x128 each
    const int l16 = lane & 15, quad = lane >> 4;

    // sibling-adjacent same-XCD map: bn-pair of each bm spaced 8 apart.
    const int xcd = bx & 7;
    const int bn  = (bx >> 3) & 1;               // 2 n-tiles of 256
    const int bm  = ((bx >> 4) << 3) | xcd;      // 128 m-tiles of 256
    const int mBase = bm * BM;
    const int nBase = bn * BN;

    // A staging: chunk c = it*512+tid, row = it*64 + (tid>>3), g = tid&7.
    const int g    = tid & 7;
    const int rsub = tid >> 3;                   // 0..63
    const int sw   = g ^ (rsub & 7);             // swizzle, it-invariant (64%8==0)
    const float* actx[4];
    const float* aout[4];
    const unsigned short* bSrc[4];
    #pragma unroll
    for (int it = 0; it < 4; ++it) {
        const int r = it * 64 + rsub;
        const int m = mBase + r;
        const int jm = jbuf[m];
        actx[it] = ctx + ((size_t)((m >> 10) * S_ + jm)) * D_ + g * 8;
        aout[it] = outp + (size_t)m * D_ - D_ + g * 8;      // add ko>=512
        // B: row&7 == rsub&7 -> source granule == sw (pre-swizzled, linear dest)
        bSrc[it] = Wbf + (size_t)(nBase + r) * K_ + sw * 8;
    }

    // attn quota: 128 rows starting here; 8 per K-iter, row = base + it*8 + wave
    const int aBase = mBase + bn * 128;

    f32x4 acc[4][8] = {};
    f32x4 fa[4][2];

#define LOAD_A(KO) do {                                                        \
    const int _koa = (KO);                                                     \
    _Pragma("unroll")                                                          \
    for (int _it = 0; _it < 4; ++_it) {                                        \
        const float* _src = (_koa < D_) ? (actx[_it] + _koa) : (aout[_it] + _koa); \
        fa[_it][0] = ((const f32x4*)_src)[0];                                  \
        fa[_it][1] = ((const f32x4*)_src)[1];                                  \
    }                                                                          \
} while (0)

    // prologue: prefetch A(0); only iter-0's cvt sees full load latency.
    LOAD_A(0);

    #pragma unroll 1
    for (int i = 0; i < NIT; ++i) {
        const int ko = i * BK;
        // ---- 1. B(i) -> LDS DMA (4 x global_load_lds, in flight across cvt)
        #pragma unroll
        for (int it = 0; it < 4; ++it) {
            __builtin_amdgcn_global_load_lds(
                (const __attribute__((address_space(1))) void*)(bSrc[it] + ko),
                (__attribute__((address_space(3))) void*)(Bs + (it * 512 + tid) * 8),
                16, 0, 0);
        }
        // ---- 2. cvt + swizzled ds_write_b128 (fa prefetched last iter)
        #pragma unroll
        for (int it = 0; it < 4; ++it) {
            union { bf16x8 v; unsigned u[4]; } pk;
            pk.u[0] = cvt2bf(fa[it][0][0], fa[it][0][1]);
            pk.u[1] = cvt2bf(fa[it][0][2], fa[it][0][3]);
            pk.u[2] = cvt2bf(fa[it][1][0], fa[it][1][1]);
            pk.u[3] = cvt2bf(fa[it][1][2], fa[it][1][3]);
            *(bf16x8*)&As[(it * 512 + rsub * 8 + sw) * 8] = pk.v;
        }
        __syncthreads();                         // drain B DMA + ds_writes

        // ---- 3a. attn one-hot rows [aBase+8i, +8): NT stores, fly under MFMA.
        {
            const int arow = aBase + i * 8 + wave;     // wave-uniform row
            const int jv = jbuf[arow];                 // scalar broadcast
            f32x4* abase = (f32x4*)(attn + (size_t)arow * S_);
            #pragma unroll
            for (int s = 0; s < 4; ++s) {
                const int col = lane + 64 * s;
                f32x4 v = {0.f, 0.f, 0.f, 0.f};
                if ((jv >> 2) == col) v[jv & 3] = 1.0f;
                __builtin_nontemporal_store(v, abase + col);
            }
        }

        // ---- 3b. prefetch A(i+1) into the same regs; flies under MFMA
        {
            const int ko2 = (ko + BK > KMAX) ? KMAX : ko + BK;   // clamped tail
            LOAD_A(ko2);
        }

        // ---- 4. MFMA phase: 2 K-steps of 32; 32 MFMA each (4mt x 8nt)
        #pragma unroll
        for (int ks = 0; ks < 2; ++ks) {
            bf16x8 af[4], bfr[8];
            const int q = ks * 4 + quad;
            #pragma unroll
            for (int mt = 0; mt < 4; ++mt) {
                const int r = wm * 64 + mt * 16 + l16;
                af[mt] = *(const bf16x8*)&As[(r * 8 + (q ^ (r & 7))) * 8];
            }
            #pragma unroll
            for (int nt = 0; nt < 8; ++nt) {
                const int rb = wn * 128 + nt * 16 + l16;
                bfr[nt] = *(const bf16x8*)&Bs[(rb * 8 + (q ^ (rb & 7))) * 8];
            }
            #pragma unroll
            for (int mt = 0; mt < 4; ++mt)
                #pragma unroll
                for (int nt = 0; nt < 8; ++nt)
                    acc[mt][nt] = __builtin_amdgcn_mfma_f32_16x16x32_bf16(
                        af[mt], bfr[nt], acc[mt][nt], 0, 0, 0);
        }
        __syncthreads();                         // drain A prefetch + attn stores
    }

#undef LOAD_A

    // ---- epilogue: fast_tanh(acc + bias), fp32 NT store
    #pragma unroll
    for (int nt = 0; nt < 8; ++nt) {
        const int n = nBase + wn * 128 + nt * 16 + l16;
        const float bv = bias[n];
        #pragma unroll
        for (int mt = 0; mt < 4; ++mt) {
            #pragma unroll
            for (int r = 0; r < 4; ++r) {
                const int m = mBase + wm * 64 + mt * 16 + quad * 4 + r;
                const float val = fast_tanh(acc[mt][nt][r] + bv);
                __builtin_nontemporal_store(val, &out[(size_t)m * N_ + n]);
            }
        }
    }
}

// ---------------------------------------------------------------------------
extern "C" void kernel_launch(void* const* d_in, const int* in_sizes, int n_in,
                              void* d_out, int out_size, void* d_ws, size_t ws_size,
                              hipStream_t stream) {
    const int*   iv   = (const int*)d_in[0];    // input_var [B,T]
    const float* outp = (const float*)d_in[1];  // output   [B,T,D]
    const float* ctx  = (const float*)d_in[2];  // context  [B,S,D]
    // d_in[3] = di (unused by reference body)
    const float* W    = (const float*)d_in[4];  // [D, 2D]
    const float* bias = (const float*)d_in[5];  // [D]

    float* out  = (float*)d_out;                       // [B,T,D]
    float* attn = out + (size_t)M_ * N_;               // [B,T,S]

    // workspace layout: j[M_] int32 | Wbf[N_*K_] bf16   (~1.1 MB total)
    int* jbuf = (int*)d_ws;
    unsigned short* Wbf = (unsigned short*)((char*)d_ws + (size_t)M_ * 4);

    align_kernel<<<B_, 64, 0, stream>>>(iv, jbuf);
    pack_w<<<(N_ * K_ / 8) / 256, 256, 0, stream>>>(W, Wbf);
    gemm_attn<<<NGEMM, 512, 0, stream>>>(Wbf, bias, out, attn, ctx, outp, jbuf);
}